// Round 7
// baseline (338.550 us; speedup 1.0000x reference)
//
#include <hip/hip_runtime.h>
#include <stdint.h>

#define BATCH 32
#define CCH   512
#define NPIX  1024
#define HEADS 8
#define QKV_M 1536   // q rows 0-511, k rows 512-1023, v rows 1024-1535

typedef short bf16x8 __attribute__((ext_vector_type(8)));
typedef float f32x4 __attribute__((ext_vector_type(4)));

__device__ inline float bf2f(unsigned short u) {
  union { float f; uint32_t i; } t; t.i = ((uint32_t)u) << 16; return t.f;
}
__device__ inline unsigned short f2bf(float f) {
  union { float f; uint32_t u; } t; t.f = f;
  uint32_t u = t.u;
  return (unsigned short)((u + 0x7FFFu + ((u >> 16) & 1u)) >> 16);
}

// async global->LDS, 16B per lane; LDS dest = wave-uniform base + lane*16
__device__ inline void gl_lds16(const unsigned short* g, unsigned short* l) {
  __builtin_amdgcn_global_load_lds(
      (const __attribute__((address_space(1))) uint32_t*)g,
      (__attribute__((address_space(3))) uint32_t*)l, 16, 0, 0);
}

// ---------------- weights fp32 -> bf16 (Wq|Wk|Wv concat, Wp separate) --------
__global__ void convert_w(const float* __restrict__ Wq, const float* __restrict__ Wk,
                          const float* __restrict__ Wv, const float* __restrict__ Wp,
                          unsigned short* __restrict__ wcat,
                          unsigned short* __restrict__ wpb) {
  int i = (blockIdx.x * 256 + threadIdx.x) * 4;
  union { ushort4 u4; unsigned short s[4]; } o;
  f32x4 a;
  a = *(const f32x4*)&Wq[i];
  for (int j = 0; j < 4; j++) o.s[j] = f2bf(a[j]);
  *(ushort4*)&wcat[i] = o.u4;
  a = *(const f32x4*)&Wk[i];
  for (int j = 0; j < 4; j++) o.s[j] = f2bf(a[j]);
  *(ushort4*)&wcat[CCH * CCH + i] = o.u4;
  a = *(const f32x4*)&Wv[i];
  for (int j = 0; j < 4; j++) o.s[j] = f2bf(a[j]);
  *(ushort4*)&wcat[2 * CCH * CCH + i] = o.u4;
  a = *(const f32x4*)&Wp[i];
  for (int j = 0; j < 4; j++) o.s[j] = f2bf(a[j]);
  *(ushort4*)&wpb[i] = o.u4;
}

// ---------------- transpose fp32 [b,R,Cc] -> bf16 [b,Cc,R] -------------------
__global__ void transpose_f2b(const float* __restrict__ in,
                              unsigned short* __restrict__ out, int R, int Cc) {
  __shared__ float tile[32][33];
  int b = blockIdx.z;
  int c0 = blockIdx.x * 32;
  int r0 = blockIdx.y * 32;
  const float* inb = in + (size_t)b * R * Cc;
  unsigned short* outb = out + (size_t)b * R * Cc;
  int tx = threadIdx.x, ty = threadIdx.y;
  for (int i = 0; i < 4; i++) {
    int r = ty + i * 8;
    tile[r][tx] = inb[(size_t)(r0 + r) * Cc + c0 + tx];
  }
  __syncthreads();
  for (int i = 0; i < 4; i++) {
    int r = ty + i * 8;
    outb[(size_t)(c0 + r) * R + r0 + tx] = f2bf(tile[tx][r]);
  }
}

// ---------------- conv_store: g = conv3x3_dw(x) -> bf16; global stats --------
__global__ void conv_store(const float* __restrict__ x,
                           const float* __restrict__ wgt,
                           unsigned short* __restrict__ gbuf,
                           float* __restrict__ s1, float* __restrict__ s2) {
  int c = blockIdx.x, b = blockIdx.y;
  __shared__ __align__(16) float plane[NPIX];
  const float* xp = x + ((size_t)b * CCH + c) * NPIX;
  unsigned short* gp = gbuf + ((size_t)b * CCH + c) * NPIX;
  *(f32x4*)&plane[threadIdx.x * 4] = *(const f32x4*)&xp[threadIdx.x * 4];
  __syncthreads();
  float w[9];
  for (int i = 0; i < 9; i++) w[i] = wgt[c * 9 + i];
  float a1 = 0.f, a2 = 0.f;
  for (int pi = 0; pi < 4; pi++) {
    int p = threadIdx.x + pi * 256;
    int h = p >> 5, wc = p & 31;
    float v = 0.f;
    for (int dh = -1; dh <= 1; dh++)
      for (int dw = -1; dw <= 1; dw++) {
        int hh = h + dh, ww = wc + dw;
        if (hh >= 0 && hh < 32 && ww >= 0 && ww < 32)
          v += w[(dh + 1) * 3 + dw + 1] * plane[hh * 32 + ww];
      }
    a1 += v; a2 += v * v;
    gp[p] = f2bf(v);
  }
  for (int off = 32; off > 0; off >>= 1) {
    a1 += __shfl_down(a1, off);
    a2 += __shfl_down(a2, off);
  }
  __shared__ float r1[4], r2[4];
  int wv = threadIdx.x >> 6;
  if ((threadIdx.x & 63) == 0) { r1[wv] = a1; r2[wv] = a2; }
  __syncthreads();
  if (threadIdx.x == 0) {
    atomicAdd(&s1[c], r1[0] + r1[1] + r1[2] + r1[3]);
    atomicAdd(&s2[c], r2[0] + r2[1] + r2[2] + r2[3]);
  }
}

// ---------------- bn_coef: fold BN into per-channel (scale, shift) -----------
__global__ void bn_coef(const float* __restrict__ s1, const float* __restrict__ s2,
                        const float* __restrict__ gamma, const float* __restrict__ beta,
                        float2* __restrict__ coef) {
  int c = blockIdx.x * 256 + threadIdx.x;
  const float invn = 1.f / 32768.f;
  float mean = s1[c] * invn;
  float var = fmaxf(s2[c] * invn - mean * mean, 0.f);
  float sc = gamma[c] * rsqrtf(var + 1e-5f);
  coef[c] = make_float2(sc, beta[c] - mean * sc);
}

// ---------------- gemm_qkv: 256x128 tile, BK=64, XOR-swizzled staging --------
// C[b][m][n] = sum_k wcat[m][k]*xT[b][n][k]; v-rows (m>=1024) gated inline:
// v *= SiLU(g*scale_c + shift_c), g = conv(x) bf16.
__launch_bounds__(256, 2)
__global__ void gemm_qkv(const unsigned short* __restrict__ A,
                         const unsigned short* __restrict__ X,
                         unsigned short* __restrict__ Cout,
                         const unsigned short* __restrict__ gbuf,
                         const float2* __restrict__ coef,
                         int N, int K) {
  __shared__ __align__(16) unsigned short As[256 * 64];
  __shared__ __align__(16) unsigned short Bs[128 * 64];
  int b  = blockIdx.z;
  int m0 = blockIdx.y * 256;
  int n0 = blockIdx.x * 128;
  const unsigned short* Xb = X + (size_t)b * N * K;
  int tid = threadIdx.x;
  int lane = tid & 63;
  int wave = tid >> 6;
  int wm = wave >> 1, wn = wave & 1;
  int quad = lane >> 4, l16 = lane & 15;

  f32x4 acc[8][4];
  f32x4 zero = {0.f, 0.f, 0.f, 0.f};
  for (int i = 0; i < 8; i++)
    for (int j = 0; j < 4; j++) acc[i][j] = zero;

  int r8 = lane >> 3;
  int sw = ((lane & 7) ^ r8) * 8;                 // XOR swizzle, coalesced
  const unsigned short* Ag = A  + (size_t)(m0 + wave * 64 + r8) * K + sw;
  const unsigned short* Xg = Xb + (size_t)(n0 + wave * 32 + r8) * K + sw;
  unsigned short* Al = &As[wave * 64 * 64];
  unsigned short* Bl = &Bs[wave * 32 * 64];

  for (int k0 = 0; k0 < K; k0 += 64) {
    for (int i = 0; i < 8; i++) gl_lds16(Ag + k0 + i * 8 * K, Al + i * 8 * 64);
    for (int i = 0; i < 4; i++) gl_lds16(Xg + k0 + i * 8 * K, Bl + i * 8 * 64);
    __syncthreads();
    for (int ks = 0; ks < 2; ks++) {
      int ch = ((ks * 4 + quad) ^ (l16 & 7)) * 8;
      bf16x8 af[8], bfr[4];
      for (int i = 0; i < 8; i++)
        af[i] = *(const bf16x8*)&As[(wm * 128 + i * 16 + l16) * 64 + ch];
      for (int j = 0; j < 4; j++)
        bfr[j] = *(const bf16x8*)&Bs[(wn * 64 + j * 16 + l16) * 64 + ch];
      for (int i = 0; i < 8; i++)
        for (int j = 0; j < 4; j++)
          acc[i][j] = __builtin_amdgcn_mfma_f32_16x16x32_bf16(af[i], bfr[j], acc[i][j], 0, 0, 0);
    }
    __syncthreads();
  }

  bool gate = (m0 >= 2 * CCH);   // whole 256-tile is v-rows or not
  for (int i = 0; i < 8; i++) {
    int gm0 = m0 + wm * 128 + i * 16 + quad * 4;
    for (int r = 0; r < 4; r++) {
      int gm = gm0 + r;
      float sc = 0.f, sh = 0.f;
      if (gate) { float2 cf = coef[gm - 2 * CCH]; sc = cf.x; sh = cf.y; }
      for (int j = 0; j < 4; j++) {
        int gn = n0 + wn * 64 + j * 16 + l16;
        float v = acc[i][j][r];
        if (gate) {
          float gg = bf2f(gbuf[((size_t)b * CCH + (gm - 2 * CCH)) * NPIX + gn]);
          float gi = gg * sc + sh;
          v *= gi / (1.f + __expf(-gi));
        }
        Cout[(size_t)b * QKV_M * N + (size_t)gm * N + gn] = f2bf(v);
      }
    }
  }
}

// ---------------- gemm_bt (proj): 128x128, BK=64, XOR swizzle, fp32 out ------
__launch_bounds__(256)
__global__ void gemm_proj(const unsigned short* __restrict__ A,
                          const unsigned short* __restrict__ X,
                          float* __restrict__ Cout,
                          const float* __restrict__ bias,
                          int M, int N, int K) {
  __shared__ __align__(16) unsigned short As[128 * 64];
  __shared__ __align__(16) unsigned short Bs[128 * 64];
  int b  = blockIdx.z;
  int m0 = blockIdx.y * 128;
  int n0 = blockIdx.x * 128;
  const unsigned short* Xb = X + (size_t)b * N * K;
  int tid = threadIdx.x;
  int lane = tid & 63;
  int wave = tid >> 6;
  int wm = wave >> 1, wn = wave & 1;
  int quad = lane >> 4, l16 = lane & 15;

  f32x4 acc[4][4];
  f32x4 zero = {0.f, 0.f, 0.f, 0.f};
  for (int i = 0; i < 4; i++)
    for (int j = 0; j < 4; j++) acc[i][j] = zero;

  int r8 = lane >> 3;
  int sw = ((lane & 7) ^ r8) * 8;
  const unsigned short* Ag = A  + (size_t)(m0 + wave * 32 + r8) * K + sw;
  const unsigned short* Xg = Xb + (size_t)(n0 + wave * 32 + r8) * K + sw;
  unsigned short* Al = &As[wave * 32 * 64];
  unsigned short* Bl = &Bs[wave * 32 * 64];

  for (int k0 = 0; k0 < K; k0 += 64) {
    for (int i = 0; i < 4; i++) {
      gl_lds16(Ag + k0 + i * 8 * K, Al + i * 8 * 64);
      gl_lds16(Xg + k0 + i * 8 * K, Bl + i * 8 * 64);
    }
    __syncthreads();
    for (int ks = 0; ks < 2; ks++) {
      int ch = ((ks * 4 + quad) ^ (l16 & 7)) * 8;
      bf16x8 af[4], bfr[4];
      for (int i = 0; i < 4; i++) {
        af[i]  = *(const bf16x8*)&As[(wm * 64 + i * 16 + l16) * 64 + ch];
        bfr[i] = *(const bf16x8*)&Bs[(wn * 64 + i * 16 + l16) * 64 + ch];
      }
      for (int i = 0; i < 4; i++)
        for (int j = 0; j < 4; j++)
          acc[i][j] = __builtin_amdgcn_mfma_f32_16x16x32_bf16(af[i], bfr[j], acc[i][j], 0, 0, 0);
    }
    __syncthreads();
  }

  for (int i = 0; i < 4; i++) {
    int gmb = m0 + wm * 64 + i * 16 + quad * 4;
    for (int j = 0; j < 4; j++) {
      int gn = n0 + wn * 64 + j * 16 + l16;
      for (int r = 0; r < 4; r++) {
        int gm = gmb + r;
        Cout[(size_t)b * M * N + (size_t)gm * N + gn] = acc[i][j][r] + bias[gm];
      }
    }
  }
}

// ---------------- attn_s: S=QK^T (fused l2norm), softmax -> P ----------------
// Each wave: full 64x64 S over its n-quarter; partials reduced via LDS planes.
__launch_bounds__(256)
__global__ void attn_s(const unsigned short* __restrict__ qkv,
                       const float* __restrict__ temp,
                       unsigned short* __restrict__ P) {
  int bh = blockIdx.x;
  int b = bh >> 3, h = bh & 7;
  const unsigned short* Q = qkv + ((size_t)b * QKV_M + h * 64) * NPIX;
  const unsigned short* K = Q + (size_t)CCH * NPIX;
  int tid = threadIdx.x, lane = tid & 63, wave = tid >> 6;
  int quad = lane >> 4, l16 = lane & 15;

  __shared__ float Sp[4][64][68];          // per-wave partial S planes
  __shared__ float qqp[4][64], kkp[4][64];
  __shared__ float redm[4][64], reds[4][64];
  __shared__ float invq[64], invk[64];

  f32x4 zero = {0.f, 0.f, 0.f, 0.f};
  f32x4 acc[4][4], accQ[4], accK[4];
  for (int i = 0; i < 4; i++) {
    accQ[i] = zero; accK[i] = zero;
    for (int j = 0; j < 4; j++) acc[i][j] = zero;
  }
  for (int nc = 0; nc < 8; nc++) {
    int n0 = wave * 256 + nc * 32;
    bf16x8 qa[4], ka[4];
    for (int i = 0; i < 4; i++) {
      qa[i] = *(const bf16x8*)&Q[(size_t)(i * 16 + l16) * NPIX + n0 + quad * 8];
      ka[i] = *(const bf16x8*)&K[(size_t)(i * 16 + l16) * NPIX + n0 + quad * 8];
    }
    for (int i = 0; i < 4; i++) {
      accQ[i] = __builtin_amdgcn_mfma_f32_16x16x32_bf16(qa[i], qa[i], accQ[i], 0, 0, 0);
      accK[i] = __builtin_amdgcn_mfma_f32_16x16x32_bf16(ka[i], ka[i], accK[i], 0, 0, 0);
    }
    for (int i = 0; i < 4; i++)
      for (int j = 0; j < 4; j++)
        acc[i][j] = __builtin_amdgcn_mfma_f32_16x16x32_bf16(qa[i], ka[j], acc[i][j], 0, 0, 0);
  }
  for (int i = 0; i < 4; i++)
    for (int j = 0; j < 4; j++)
      for (int r = 0; r < 4; r++)
        Sp[wave][i * 16 + quad * 4 + r][j * 16 + l16] = acc[i][j][r];
  for (int i = 0; i < 4; i++)
    for (int r = 0; r < 4; r++)
      if (l16 == quad * 4 + r) {
        qqp[wave][i * 16 + l16] = accQ[i][r];
        kkp[wave][i * 16 + l16] = accK[i][r];
      }
  __syncthreads();
  if (tid < 64)
    invq[tid] = 1.f / fmaxf(sqrtf(qqp[0][tid] + qqp[1][tid] + qqp[2][tid] + qqp[3][tid]), 1e-12f);
  else if (tid < 128) {
    int t = tid - 64;
    invk[t] = 1.f / fmaxf(sqrtf(kkp[0][t] + kkp[1][t] + kkp[2][t] + kkp[3][t]), 1e-12f);
  }
  __syncthreads();

  int row = tid & 63, seg = tid >> 6;
  float fq = temp[h] * invq[row];
  float v[16], pm = -1e30f;
  for (int i = 0; i < 16; i++) {
    int e = seg * 16 + i;
    float sv = Sp[0][row][e] + Sp[1][row][e] + Sp[2][row][e] + Sp[3][row][e];
    v[i] = sv * fq * invk[e];
    pm = fmaxf(pm, v[i]);
  }
  redm[seg][row] = pm;
  __syncthreads();
  float m = fmaxf(fmaxf(redm[0][row], redm[1][row]),
                  fmaxf(redm[2][row], redm[3][row]));
  float ps = 0.f;
  for (int i = 0; i < 16; i++) { v[i] = __expf(v[i] - m); ps += v[i]; }
  reds[seg][row] = ps;
  __syncthreads();
  float inv = 1.f / (reds[0][row] + reds[1][row] + reds[2][row] + reds[3][row]);
  union { uint4 q4[2]; unsigned short s[16]; } u;
  for (int i = 0; i < 16; i++) u.s[i] = f2bf(v[i] * inv);
  unsigned short* Pp = P + ((size_t)bh * 64 + row) * 64 + seg * 16;
  *(uint4*)&Pp[0] = u.q4[0];
  *(uint4*)&Pp[8] = u.q4[1];
}

// ---------------- attn_o: O^T[n][d] = sum_e V^T[n][e] P[d][e] ----------------
__launch_bounds__(256)
__global__ void attn_o(const unsigned short* __restrict__ qkv,
                       const unsigned short* __restrict__ P,
                       unsigned short* __restrict__ aoT) {
  int blk = blockIdx.x;
  int nc = blk & 3, bh = blk >> 2;
  int b = bh >> 3, h = bh & 7;
  const unsigned short* V = qkv + ((size_t)b * QKV_M + 2 * CCH + h * 64) * NPIX;
  unsigned short* Ob = aoT + (size_t)b * NPIX * CCH + h * 64;
  int tid = threadIdx.x, lane = tid & 63, wave = tid >> 6;
  int quad = lane >> 4, l16 = lane & 15;

  __shared__ __align__(16) unsigned short Vt[4][16][72];
  __shared__ __align__(16) unsigned short Ot[4][16][72];

  const unsigned short* Pb = P + (size_t)bh * 64 * 64;
  bf16x8 Pf[4][2];
  for (int j = 0; j < 4; j++)
    for (int ks = 0; ks < 2; ks++)
      Pf[j][ks] = *(const bf16x8*)&Pb[(j * 16 + l16) * 64 + ks * 32 + quad * 8];

  f32x4 zero = {0.f, 0.f, 0.f, 0.f};
  int e1 = lane >> 1, noff = (lane & 1) * 8;
  int nbase = nc * 256 + wave * 64;
  int orow = lane >> 3, ocol = (lane & 7) * 8;

  union { uint4 q; unsigned short s[8]; } g0, g1, c0, c1;
  g0.q = *(const uint4*)&V[(size_t)e1 * NPIX + nbase + noff];
  g1.q = *(const uint4*)&V[(size_t)(e1 + 32) * NPIX + nbase + noff];
#pragma unroll
  for (int nt = 0; nt < 4; nt++) {
    int n0 = nbase + nt * 16;
    c0 = g0; c1 = g1;
    if (nt < 3) {
      g0.q = *(const uint4*)&V[(size_t)e1 * NPIX + n0 + 16 + noff];
      g1.q = *(const uint4*)&V[(size_t)(e1 + 32) * NPIX + n0 + 16 + noff];
    }
    for (int jj = 0; jj < 8; jj++) {
      Vt[wave][noff + jj][e1]      = c0.s[jj];
      Vt[wave][noff + jj][e1 + 32] = c1.s[jj];
    }
    bf16x8 Af0 = *(const bf16x8*)&Vt[wave][l16][quad * 8];
    bf16x8 Af1 = *(const bf16x8*)&Vt[wave][l16][32 + quad * 8];
    f32x4 oacc[4];
    for (int j = 0; j < 4; j++) {
      oacc[j] = __builtin_amdgcn_mfma_f32_16x16x32_bf16(Af0, Pf[j][0], zero, 0, 0, 0);
      oacc[j] = __builtin_amdgcn_mfma_f32_16x16x32_bf16(Af1, Pf[j][1], oacc[j], 0, 0, 0);
    }
    for (int j = 0; j < 4; j++)
      for (int r = 0; r < 4; r++)
        Ot[wave][quad * 4 + r][j * 16 + l16] = f2bf(oacc[j][r]);
    uint4 o0 = *(const uint4*)&Ot[wave][orow][ocol];
    uint4 o1 = *(const uint4*)&Ot[wave][orow + 8][ocol];
    *(uint4*)&Ob[(size_t)(n0 + orow) * CCH + ocol] = o0;
    *(uint4*)&Ob[(size_t)(n0 + orow + 8) * CCH + ocol] = o1;
  }
}

// ---------------------------------------------------------------------------
extern "C" void kernel_launch(void* const* d_in, const int* in_sizes, int n_in,
                              void* d_out, int out_size, void* d_ws, size_t ws_size,
                              hipStream_t stream) {
  const float* x     = (const float*)d_in[0];
  const float* Wq    = (const float*)d_in[1];
  const float* Wk    = (const float*)d_in[2];
  const float* Wv    = (const float*)d_in[3];
  const float* dww   = (const float*)d_in[4];
  const float* gamma = (const float*)d_in[5];
  const float* beta  = (const float*)d_in[6];
  const float* temp  = (const float*)d_in[7];
  const float* Wp    = (const float*)d_in[8];
  const float* bp    = (const float*)d_in[9];
  float* out = (float*)d_out;

  char* ws = (char*)d_ws;
  unsigned short* wcat = (unsigned short*)ws;             // [1536,512] bf16
  unsigned short* wpb  = wcat + (size_t)QKV_M * CCH;      // [512,512] bf16
  float* s1 = (float*)(wpb + (size_t)CCH * CCH);
  float* s2 = s1 + CCH;
  float2* coef = (float2*)(s2 + CCH);                     // [512] (scale,shift)
  unsigned short* Pbuf = (unsigned short*)(coef + CCH);   // [B*H,64,64] bf16
  unsigned short* gbuf = Pbuf + (size_t)BATCH * HEADS * 64 * 64;  // [B,C,N] bf16
  char* dyn = (char*)(gbuf + (size_t)BATCH * CCH * NPIX);
  size_t fixed = (size_t)(dyn - ws);
  size_t per_b = ((size_t)NPIX * CCH + (size_t)QKV_M * NPIX) * 2;  // 4 MB/batch
  int BC = BATCH;
  while (BC > 1 && fixed + (size_t)BC * per_b > ws_size) BC >>= 1;
  unsigned short* xT  = (unsigned short*)dyn;                  // [BC,N,C]; reused as aoT
  unsigned short* qkv = xT + (size_t)BC * NPIX * CCH;          // [BC,1536,N]

  convert_w<<<CCH * CCH / 1024, 256, 0, stream>>>(Wq, Wk, Wv, Wp, wcat, wpb);
  hipMemsetAsync(s1, 0, 2 * CCH * sizeof(float), stream);
  conv_store<<<dim3(CCH, BATCH), 256, 0, stream>>>(x, dww, gbuf, s1, s2);
  bn_coef<<<CCH / 256, 256, 0, stream>>>(s1, s2, gamma, beta, coef);

  for (int b0 = 0; b0 < BATCH; b0 += BC) {
    const float* xc = x + (size_t)b0 * CCH * NPIX;
    float* outc = out + (size_t)b0 * CCH * NPIX;
    const unsigned short* gc = gbuf + (size_t)b0 * CCH * NPIX;
    transpose_f2b<<<dim3(NPIX / 32, CCH / 32, BC), dim3(32, 8), 0, stream>>>(
        xc, xT, CCH, NPIX);
    gemm_qkv<<<dim3(NPIX / 128, QKV_M / 256, BC), 256, 0, stream>>>(
        wcat, xT, qkv, gc, coef, NPIX, CCH);
    attn_s<<<BC * HEADS, 256, 0, stream>>>(qkv, temp, Pbuf);
    attn_o<<<BC * HEADS * 4, 256, 0, stream>>>(qkv, Pbuf, xT);  // aoT overwrites xT
    gemm_proj<<<dim3(NPIX / 128, CCH / 128, BC), 256, 0, stream>>>(
        wpb, xT, outc, bp, CCH, NPIX, CCH);
  }
}